// Round 1
// 682.511 us; speedup vs baseline: 1.0188x; 1.0188x over previous
//
#include <hip/hip_runtime.h>
#include <hip/hip_bf16.h>

// SWIN attention, round 5.
// qkvattn was latency-bound (MfmaUtil 13%, Occ 22%, HBM 11%): ~80 scattered
// global loads/wave, 2 waves/SIMD. Changes:
//  (1) A-tile (64x256, shared by all 4 waves) staged ONCE into swizzled LDS,
//      aliased over the per-wave attn regions (zero extra LDS, 2 barriers).
//  (2) LDS 59392->49152 B (swizzled strides 32/64 instead of padded 40/72)
//      + launch_bounds(256,3) -> 3 blocks/CU = 12 waves/CU.
//  (3) convert kernels deleted: pass0 gathers fp32 x directly during staging;
//      pass0 proj scatters bf16 straight into pass1's window layout
//      (h'=(h-4)&63 permutation). Kills 2 dispatches + fp32 out round-trip.

typedef short short8 __attribute__((ext_vector_type(8)));
typedef float floatx4 __attribute__((ext_vector_type(4)));

#define SCALE 0.17677669529663687f  // 1/sqrt(32)
#define NEGM  -1e9f

__device__ __forceinline__ ushort f2b(float f) {  // RNE fp32->bf16
  uint u = __float_as_uint(f);
  return (ushort)((u + 0x7FFFu + ((u >> 16) & 1u)) >> 16);
}

__device__ __forceinline__ void win_coords(int pass, int gw, int s,
                                           int& m, int& h, int& w) {
  m = gw >> 6;
  int wy = (gw >> 3) & 7, wx = gw & 7;
  h = wy * 8 + (s >> 3);
  w = wx * 8 + (s & 7);
  if (pass) { h = (h + 4) & 63; w = (w + 4) & 63; }
}

__device__ __forceinline__ int region_id(int wy, int wx, int s) {
  int rh = (wy == 7) ? (((s >> 3) >= 4) ? 2 : 1) : 0;
  int rw = (wx == 7) ? (((s & 7) >= 4) ? 2 : 1) : 0;
  return rh * 3 + rw;
}

// ---- swizzled LDS index helpers (ushort units) ----
// As [64 rows][32 granules of 8]: granule g -> g ^ (row&7). Conflict-free
// for af reads (per quarter: 8 bank-groups x 2 lanes) and staging writes.
__device__ __forceinline__ int a_idx(int row, int g) {
  return row * 256 + ((g ^ (row & 7)) << 3);
}
// Qs/Ks [64 tok][32 d], 4 granules: g -> g ^ ((tok>>2)&3).
__device__ __forceinline__ int qk_idx(int tok, int d) {
  return tok * 32 + ((((d >> 3) ^ (tok >> 2)) & 3) << 3) + (d & 7);
}
// Vt [32 d][64 tok], 8 granules: g -> g ^ (d&7).
__device__ __forceinline__ int v_idx(int d, int tok) {
  return d * 64 + ((((tok >> 3) ^ d) & 7) << 3) + (tok & 7);
}
// Ps [64 row][64 col], 8 granules: g -> g ^ (row&7).
__device__ __forceinline__ int p_idx(int row, int col) {
  return row * 64 + ((((col >> 3) ^ row) & 7) << 3) + (col & 7);
}

// ---------------------------------------------------------------------------
// K0: weights -> k-contiguous bf16.
// ---------------------------------------------------------------------------
__global__ __launch_bounds__(256) void wtrans_kernel(
    const float* __restrict__ wqkv, const float* __restrict__ wo,
    ushort* __restrict__ wqkvT, ushort* __restrict__ woT) {
  const int t = threadIdx.x, b = blockIdx.x;
  if (b < 768) {
    wqkvT[b * 256 + t] = f2b(wqkv[t * 768 + b]);
  } else {
    const int n = b - 768;
    woT[n * 256 + t] = f2b(wo[t * 256 + n]);
  }
}

// ---------------------------------------------------------------------------
// K1: fused qkv + attention. grid CW*2 x 256 (4 waves = heads 0-3 or 4-7).
// Block LDS 49152 B = 4 wave regions of 6144 ushorts:
//   Qs[2048] @ +0 | Ks[2048] @ +2048 | Vt[2048] @ +4096 ; Ps[4096] aliases Q|K.
// As (16384 ushorts) aliases wave regions 0-2 during the GEMM phase only.
// ---------------------------------------------------------------------------
__global__ __launch_bounds__(256, 3) void qkvattn_kernel(
    const float* __restrict__ x, const ushort* __restrict__ xwc,
    const ushort* __restrict__ wqkvT, const float* __restrict__ bqkv,
    ushort* __restrict__ attn_out, int w0, int pass) {
  __shared__ ushort sm[24576];
  const int t = threadIdx.x;
  const int wv = t >> 6, lane = t & 63;
  const int quad = lane >> 4, l15 = lane & 15;
  const int wi = blockIdx.x >> 1;
  const int hh = (blockIdx.x & 1) * 4 + wv;
  const int gw = w0 + wi;

  ushort* As = sm;
  ushort* Qs = sm + wv * 6144;
  ushort* Ks = Qs + 2048;
  ushort* Vt = Qs + 4096;
  ushort* Ps = Qs;

  // ---- stage A-tile (64 tok x 256 ch) into swizzled LDS, cooperatively ----
  {
    const int rr = t >> 5;   // row-within-8-group
    const int gg = t & 31;   // granule (8 ch)
    if (pass) {
      // linear bf16 window rows (written by pass-0 proj in pass-1 order)
      const ushort* src = xwc + (size_t)wi * 16384 + rr * 256 + gg * 8;
#pragma unroll
      for (int j = 0; j < 8; ++j) {
        uint4 v = *(const uint4*)(src + j * 2048);  // row j*8+rr
        *(uint4*)&As[a_idx(j * 8 + rr, gg)] = v;
      }
    } else {
      // gather fp32 x: token s = j*8+rr -> h = wy*8+j, w = wx*8+rr
      const int m = gw >> 6;
      const int hb = ((gw >> 3) & 7) * 8;
      const int w = (gw & 7) * 8 + rr;
      const float* src = x + (size_t)((m * 64 + hb) * 64 + w) * 256 + gg * 8;
#pragma unroll
      for (int j = 0; j < 8; ++j) {
        float4 a = *(const float4*)(src + (size_t)j * 16384);
        float4 b = *(const float4*)(src + (size_t)j * 16384 + 4);
        short8 o;
        o[0] = (short)f2b(a.x); o[1] = (short)f2b(a.y);
        o[2] = (short)f2b(a.z); o[3] = (short)f2b(a.w);
        o[4] = (short)f2b(b.x); o[5] = (short)f2b(b.y);
        o[6] = (short)f2b(b.z); o[7] = (short)f2b(b.w);
        *(short8*)&As[a_idx(j * 8 + rr, gg)] = o;
      }
    }
  }
  __syncthreads();

  // ---- qkv GEMM for this head: M=64 tok, N=96 (Q|K|V x 32d), K=256 ----
  floatx4 acc[4][6];
#pragma unroll
  for (int i = 0; i < 4; ++i)
#pragma unroll
    for (int j = 0; j < 6; ++j) acc[i][j] = {0.f, 0.f, 0.f, 0.f};

  const ushort* brow[6];
#pragma unroll
  for (int nt = 0; nt < 6; ++nt) {
    const int n = (nt >> 1) * 256 + hh * 32 + (nt & 1) * 16 + l15;
    brow[nt] = wqkvT + (size_t)n * 256;
  }

#pragma unroll
  for (int ks = 0; ks < 8; ++ks) {
    const int k0 = ks * 32 + quad * 8;
    short8 af[4], bf[6];
#pragma unroll
    for (int mi = 0; mi < 4; ++mi)
      af[mi] = *(const short8*)&As[a_idx(mi * 16 + l15, ks * 4 + quad)];
#pragma unroll
    for (int nt = 0; nt < 6; ++nt)
      bf[nt] = *(const short8*)(brow[nt] + k0);
#pragma unroll
    for (int mi = 0; mi < 4; ++mi)
#pragma unroll
      for (int nt = 0; nt < 6; ++nt)
        acc[mi][nt] = __builtin_amdgcn_mfma_f32_16x16x32_bf16(
            af[mi], bf[nt], acc[mi][nt], 0, 0, 0);
  }
  __syncthreads();  // As dead; wave regions may now be overwritten

  // epilogue: +bias, bf16, into wave-private swizzled LDS
#pragma unroll
  for (int nt = 0; nt < 6; ++nt) {
    const int d = (nt & 1) * 16 + l15;
    const float bias = bqkv[(nt >> 1) * 256 + hh * 32 + d];
#pragma unroll
    for (int mi = 0; mi < 4; ++mi)
#pragma unroll
      for (int r = 0; r < 4; ++r) {
        const int tok = mi * 16 + quad * 4 + r;
        const ushort v = f2b(acc[mi][nt][r] + bias);
        if (nt < 2)      Qs[qk_idx(tok, d)] = v;
        else if (nt < 4) Ks[qk_idx(tok, d)] = v;
        else             Vt[v_idx(d, tok)] = v;
      }
  }

  // ---- QK^T ----
  short8 qf[4], kf[4];
#pragma unroll
  for (int i = 0; i < 4; ++i) {
    const int row = i * 16 + l15;
    qf[i] = *(const short8*)&Qs[qk_idx(row, quad * 8)];
    kf[i] = *(const short8*)&Ks[qk_idx(row, quad * 8)];
  }
  floatx4 S[4][4];
#pragma unroll
  for (int i = 0; i < 4; ++i)
#pragma unroll
    for (int j = 0; j < 4; ++j) S[i][j] = {0.f, 0.f, 0.f, 0.f};
#pragma unroll
  for (int mi = 0; mi < 4; ++mi)
#pragma unroll
    for (int nj = 0; nj < 4; ++nj)
      S[mi][nj] = __builtin_amdgcn_mfma_f32_16x16x32_bf16(
          qf[mi], kf[nj], S[mi][nj], 0, 0, 0);

  // scale + swin mask
  const int wy = (gw >> 3) & 7, wx = gw & 7;
#pragma unroll
  for (int mi = 0; mi < 4; ++mi)
#pragma unroll
    for (int nj = 0; nj < 4; ++nj)
#pragma unroll
      for (int r = 0; r < 4; ++r) S[mi][nj][r] *= SCALE;
  if (pass) {
    int ridc[4];
#pragma unroll
    for (int nj = 0; nj < 4; ++nj) ridc[nj] = region_id(wy, wx, nj * 16 + l15);
#pragma unroll
    for (int mi = 0; mi < 4; ++mi)
#pragma unroll
      for (int r = 0; r < 4; ++r) {
        const int rr = region_id(wy, wx, mi * 16 + quad * 4 + r);
#pragma unroll
        for (int nj = 0; nj < 4; ++nj)
          if (rr != ridc[nj]) S[mi][nj][r] += NEGM;
      }
  }

  // softmax per row; write P (bf16) to Ps (aliases Q|K, both now dead)
#pragma unroll
  for (int mi = 0; mi < 4; ++mi) {
#pragma unroll
    for (int r = 0; r < 4; ++r) {
      float mx = fmaxf(fmaxf(S[mi][0][r], S[mi][1][r]),
                       fmaxf(S[mi][2][r], S[mi][3][r]));
#pragma unroll
      for (int o = 1; o < 16; o <<= 1) mx = fmaxf(mx, __shfl_xor(mx, o));
      float sm_ = 0.f;
#pragma unroll
      for (int nj = 0; nj < 4; ++nj) {
        float e = __expf(S[mi][nj][r] - mx);
        S[mi][nj][r] = e;
        sm_ += e;
      }
#pragma unroll
      for (int o = 1; o < 16; o <<= 1) sm_ += __shfl_xor(sm_, o);
      const float inv = 1.f / sm_;
      const int row = mi * 16 + quad * 4 + r;
#pragma unroll
      for (int nj = 0; nj < 4; ++nj)
        Ps[p_idx(row, nj * 16 + l15)] = f2b(S[mi][nj][r] * inv);
    }
  }

  // ---- PV: A = P (LDS), B = V^T (LDS) ----
  floatx4 O[4][2];
#pragma unroll
  for (int i = 0; i < 4; ++i) {
    O[i][0] = {0.f, 0.f, 0.f, 0.f};
    O[i][1] = {0.f, 0.f, 0.f, 0.f};
  }
#pragma unroll
  for (int ks = 0; ks < 2; ++ks) {
    short8 bfr[2];
#pragma unroll
    for (int n2 = 0; n2 < 2; ++n2)
      bfr[n2] = *(const short8*)&Vt[v_idx(n2 * 16 + l15, ks * 32 + quad * 8)];
#pragma unroll
    for (int mi = 0; mi < 4; ++mi) {
      short8 af2 = *(const short8*)&Ps[p_idx(mi * 16 + l15, ks * 32 + quad * 8)];
#pragma unroll
      for (int n2 = 0; n2 < 2; ++n2)
        O[mi][n2] = __builtin_amdgcn_mfma_f32_16x16x32_bf16(
            af2, bfr[n2], O[mi][n2], 0, 0, 0);
    }
  }

  // store bf16 [win][tok][256]
  ushort* ob = attn_out + (size_t)wi * 16384 + hh * 32;
#pragma unroll
  for (int mi = 0; mi < 4; ++mi)
#pragma unroll
    for (int r = 0; r < 4; ++r) {
      const int s = mi * 16 + quad * 4 + r;
      ob[s * 256 + l15]      = f2b(O[mi][0][r]);
      ob[s * 256 + 16 + l15] = f2b(O[mi][1][r]);
    }
}

// ---------------------------------------------------------------------------
// K2: out-proj GEMM (bf16 A). pass0: scatter bf16 into pass-1 window layout
// of xw (fuses window_reverse + roll + window_partition). pass1: fp32 out.
// ---------------------------------------------------------------------------
__global__ __launch_bounds__(256) void proj_mfma_kernel(
    const ushort* __restrict__ attn, const ushort* __restrict__ BT,
    const float* __restrict__ bo, float* __restrict__ out,
    ushort* __restrict__ xw, int w0, int pass) {
  __shared__ ushort As[128][72];
  __shared__ ushort Bs[128][72];
  const int t = threadIdx.x;
  const int lane = t & 63, wv = t >> 6;
  const int wm = wv >> 1, wn = wv & 1;
  const int quad = lane >> 4, l15 = lane & 15;
  const int sr = t >> 1, sh = (t & 1) * 32;
  const int bn0 = blockIdx.x * 128, row0 = blockIdx.y * 128;

  floatx4 acc[4][4];
#pragma unroll
  for (int i = 0; i < 4; ++i)
#pragma unroll
    for (int j = 0; j < 4; ++j) acc[i][j] = {0.f, 0.f, 0.f, 0.f};

  const ushort* arow = attn + (size_t)(row0 + sr) * 256 + sh;
  const ushort* brow = BT + (size_t)(bn0 + sr) * 256 + sh;

  for (int kc = 0; kc < 4; ++kc) {
    const int k0 = kc * 64;
#pragma unroll
    for (int u = 0; u < 4; ++u) {
      *(uint4*)&As[sr][sh + u * 8] = *(const uint4*)(arow + k0 + u * 8);
      *(uint4*)&Bs[sr][sh + u * 8] = *(const uint4*)(brow + k0 + u * 8);
    }
    __syncthreads();
#pragma unroll
    for (int ks = 0; ks < 2; ++ks) {
      const int ko = ks * 32 + quad * 8;
      short8 af[4], bf[4];
#pragma unroll
      for (int i = 0; i < 4; ++i) {
        af[i] = *(const short8*)&As[wm * 64 + i * 16 + l15][ko];
        bf[i] = *(const short8*)&Bs[wn * 64 + i * 16 + l15][ko];
      }
#pragma unroll
      for (int mi = 0; mi < 4; ++mi)
#pragma unroll
        for (int nj = 0; nj < 4; ++nj)
          acc[mi][nj] = __builtin_amdgcn_mfma_f32_16x16x32_bf16(
              af[mi], bf[nj], acc[mi][nj], 0, 0, 0);
    }
    __syncthreads();
  }

  float bias[4];
  int ncol[4];
#pragma unroll
  for (int nj = 0; nj < 4; ++nj) {
    ncol[nj] = bn0 + wn * 64 + nj * 16 + l15;
    bias[nj] = bo[ncol[nj]];
  }
#pragma unroll
  for (int mi = 0; mi < 4; ++mi)
#pragma unroll
    for (int r = 0; r < 4; ++r) {
      const int gr = row0 + wm * 64 + mi * 16 + quad * 4 + r;
      int m, h, w;
      win_coords(pass, w0 + (gr >> 6), gr & 63, m, h, w);
      if (pass == 0) {
        // y[m,h,w] feeds pass-1 window token with h'=(h-4)&63, w'=(w-4)&63
        const int h2 = (h - 4) & 63, w2 = (w - 4) & 63;
        const int row2 = ((m * 64 + (h2 >> 3) * 8 + (w2 >> 3)) << 6) +
                         (h2 & 7) * 8 + (w2 & 7);
        ushort* xrow = xw + (size_t)row2 * 256;
#pragma unroll
        for (int nj = 0; nj < 4; ++nj)
          xrow[ncol[nj]] = f2b(acc[mi][nj][r] + bias[nj]);
      } else {
        float* orow = out + (size_t)((m * 64 + h) * 64 + w) * 256;
#pragma unroll
        for (int nj = 0; nj < 4; ++nj)
          orow[ncol[nj]] = acc[mi][nj][r] + bias[nj];
      }
    }
}

// ---------------------------------------------------------------------------
extern "C" void kernel_launch(void* const* d_in, const int* in_sizes, int n_in,
                              void* d_out, int out_size, void* d_ws, size_t ws_size,
                              hipStream_t stream) {
  (void)in_sizes; (void)n_in; (void)out_size;
  const float* x    = (const float*)d_in[0];
  const float* wqkv = (const float*)d_in[1];
  const float* bqkv = (const float*)d_in[2];
  const float* wo   = (const float*)d_in[3];
  const float* bo   = (const float*)d_in[4];
  float* out = (float*)d_out;

  // ws: wqkvT(384K) | woT(128K) | xw bf16 (64M, pass-1 input) | attn chunks
  ushort* wqkvT = (ushort*)d_ws;
  ushort* woT   = (ushort*)((char*)d_ws + 393216);
  ushort* xw    = (ushort*)((char*)d_ws + 524288);
  char* chunkbase = (char*)d_ws + 524288 + 67108864;
  size_t fixed = 524288 + 67108864;
  size_t rem = (ws_size > fixed) ? (ws_size - fixed) : 0;
  int S = 1;
  while (S < 1024 && (size_t)(2048 / S) * 32768 > rem) S <<= 1;
  const int CW = 2048 / S;
  ushort* attnws = (ushort*)chunkbase;  // CW*32768 B

  wtrans_kernel<<<dim3(1024), dim3(256), 0, stream>>>(wqkv, wo, wqkvT, woT);

  for (int pass = 0; pass < 2; ++pass) {
    for (int c = 0; c < S; ++c) {
      const int w0 = c * CW;
      qkvattn_kernel<<<dim3(CW * 2), dim3(256), 0, stream>>>(
          x, xw + (size_t)w0 * 16384, wqkvT, bqkv, attnws, w0, pass);
      proj_mfma_kernel<<<dim3(2, CW / 2), dim3(256), 0, stream>>>(
          attnws, woT, bo, out, xw, w0, pass);
    }
  }
}

// Round 2
// 623.165 us; speedup vs baseline: 1.1158x; 1.0952x over previous
//
#include <hip/hip_runtime.h>
#include <hip/hip_bf16.h>

// SWIN attention, round 6.
// Round-5 regression diagnosed: launch_bounds(256,3) + acc[4][6] (96 regs
// live) => scratch spill (VGPR=84, +166MB/dispatch scratch writes).
// Fix: split qkv GEMM into 3 K-sweeps (Q,K,V), acc[4][2] each; pack each
// group's bf16 result 2-per-VGPR (48 regs total) until the barrier that
// retires the As alias; then unpack into wave-private LDS. Peak liveness
// ~130 regs < 168 cap -> no spill at 3 blocks/CU.

typedef short short8 __attribute__((ext_vector_type(8)));
typedef float floatx4 __attribute__((ext_vector_type(4)));

#define SCALE 0.17677669529663687f  // 1/sqrt(32)
#define NEGM  -1e9f

__device__ __forceinline__ ushort f2b(float f) {  // RNE fp32->bf16
  uint u = __float_as_uint(f);
  return (ushort)((u + 0x7FFFu + ((u >> 16) & 1u)) >> 16);
}

__device__ __forceinline__ void win_coords(int pass, int gw, int s,
                                           int& m, int& h, int& w) {
  m = gw >> 6;
  int wy = (gw >> 3) & 7, wx = gw & 7;
  h = wy * 8 + (s >> 3);
  w = wx * 8 + (s & 7);
  if (pass) { h = (h + 4) & 63; w = (w + 4) & 63; }
}

__device__ __forceinline__ int region_id(int wy, int wx, int s) {
  int rh = (wy == 7) ? (((s >> 3) >= 4) ? 2 : 1) : 0;
  int rw = (wx == 7) ? (((s & 7) >= 4) ? 2 : 1) : 0;
  return rh * 3 + rw;
}

// ---- swizzled LDS index helpers (ushort units) ----
__device__ __forceinline__ int a_idx(int row, int g) {
  return row * 256 + ((g ^ (row & 7)) << 3);
}
__device__ __forceinline__ int qk_idx(int tok, int d) {
  return tok * 32 + ((((d >> 3) ^ (tok >> 2)) & 3) << 3) + (d & 7);
}
__device__ __forceinline__ int v_idx(int d, int tok) {
  return d * 64 + ((((tok >> 3) ^ d) & 7) << 3) + (tok & 7);
}
__device__ __forceinline__ int p_idx(int row, int col) {
  return row * 64 + ((((col >> 3) ^ row) & 7) << 3) + (col & 7);
}

// ---------------------------------------------------------------------------
// K0: weights -> k-contiguous bf16.
// ---------------------------------------------------------------------------
__global__ __launch_bounds__(256) void wtrans_kernel(
    const float* __restrict__ wqkv, const float* __restrict__ wo,
    ushort* __restrict__ wqkvT, ushort* __restrict__ woT) {
  const int t = threadIdx.x, b = blockIdx.x;
  if (b < 768) {
    wqkvT[b * 256 + t] = f2b(wqkv[t * 768 + b]);
  } else {
    const int n = b - 768;
    woT[n * 256 + t] = f2b(wo[t * 256 + n]);
  }
}

// ---------------------------------------------------------------------------
// K1: fused qkv + attention. grid CW*2 x 256 (4 waves = heads 0-3 or 4-7).
// Block LDS 49152 B = 4 wave regions of 6144 ushorts:
//   Qs[2048] | Ks[2048] | Vt[2048] ; Ps[4096] aliases Q|K.
// As (16384 ushorts) aliases wave regions 0-2 during the GEMM phase only.
// ---------------------------------------------------------------------------
__global__ __launch_bounds__(256, 3) void qkvattn_kernel(
    const float* __restrict__ x, const ushort* __restrict__ xwc,
    const ushort* __restrict__ wqkvT, const float* __restrict__ bqkv,
    ushort* __restrict__ attn_out, int w0, int pass) {
  __shared__ ushort sm[24576];
  const int t = threadIdx.x;
  const int wv = t >> 6, lane = t & 63;
  const int quad = lane >> 4, l15 = lane & 15;
  const int wi = blockIdx.x >> 1;
  const int hh = (blockIdx.x & 1) * 4 + wv;
  const int gw = w0 + wi;

  ushort* As = sm;
  ushort* Qs = sm + wv * 6144;
  ushort* Ks = Qs + 2048;
  ushort* Vt = Qs + 4096;
  ushort* Ps = Qs;

  // ---- stage A-tile (64 tok x 256 ch) into swizzled LDS, cooperatively ----
  {
    const int rr = t >> 5;   // row-within-8-group
    const int gg = t & 31;   // granule (8 ch)
    if (pass) {
      const ushort* src = xwc + (size_t)wi * 16384 + rr * 256 + gg * 8;
#pragma unroll
      for (int j = 0; j < 8; ++j) {
        uint4 v = *(const uint4*)(src + j * 2048);  // row j*8+rr
        *(uint4*)&As[a_idx(j * 8 + rr, gg)] = v;
      }
    } else {
      const int m = gw >> 6;
      const int hb = ((gw >> 3) & 7) * 8;
      const int w = (gw & 7) * 8 + rr;
      const float* src = x + (size_t)((m * 64 + hb) * 64 + w) * 256 + gg * 8;
#pragma unroll
      for (int j = 0; j < 8; ++j) {
        float4 a = *(const float4*)(src + (size_t)j * 16384);
        float4 b = *(const float4*)(src + (size_t)j * 16384 + 4);
        short8 o;
        o[0] = (short)f2b(a.x); o[1] = (short)f2b(a.y);
        o[2] = (short)f2b(a.z); o[3] = (short)f2b(a.w);
        o[4] = (short)f2b(b.x); o[5] = (short)f2b(b.y);
        o[6] = (short)f2b(b.z); o[7] = (short)f2b(b.w);
        *(short8*)&As[a_idx(j * 8 + rr, gg)] = o;
      }
    }
  }
  __syncthreads();

  // ---- qkv GEMM: 3 K-sweeps (Q,K,V), M=64, N=32 (2 tiles), K=256 each ----
  // Results packed bf16 2-per-VGPR until the barrier retires As.
  uint pk[3][16];
#pragma unroll
  for (int g = 0; g < 3; ++g) {
    floatx4 acc[4][2];
#pragma unroll
    for (int i = 0; i < 4; ++i) {
      acc[i][0] = {0.f, 0.f, 0.f, 0.f};
      acc[i][1] = {0.f, 0.f, 0.f, 0.f};
    }
    const ushort* b0 = wqkvT + (size_t)(g * 256 + hh * 32 + l15) * 256;
    const ushort* b1 = b0 + 16 * 256;
#pragma unroll
    for (int ks = 0; ks < 8; ++ks) {
      const int k0 = ks * 32 + quad * 8;
      short8 af[4], bf[2];
#pragma unroll
      for (int mi = 0; mi < 4; ++mi)
        af[mi] = *(const short8*)&As[a_idx(mi * 16 + l15, ks * 4 + quad)];
      bf[0] = *(const short8*)(b0 + k0);
      bf[1] = *(const short8*)(b1 + k0);
#pragma unroll
      for (int mi = 0; mi < 4; ++mi) {
        acc[mi][0] = __builtin_amdgcn_mfma_f32_16x16x32_bf16(
            af[mi], bf[0], acc[mi][0], 0, 0, 0);
        acc[mi][1] = __builtin_amdgcn_mfma_f32_16x16x32_bf16(
            af[mi], bf[1], acc[mi][1], 0, 0, 0);
      }
    }
    const float bias0 = bqkv[g * 256 + hh * 32 + l15];
    const float bias1 = bqkv[g * 256 + hh * 32 + 16 + l15];
#pragma unroll
    for (int nt2 = 0; nt2 < 2; ++nt2) {
      const float bias = nt2 ? bias1 : bias0;
#pragma unroll
      for (int mi = 0; mi < 4; ++mi)
#pragma unroll
        for (int rp = 0; rp < 2; ++rp) {
          const uint lo = f2b(acc[mi][nt2][rp * 2] + bias);
          const uint hi = f2b(acc[mi][nt2][rp * 2 + 1] + bias);
          pk[g][nt2 * 8 + mi * 2 + rp] = lo | (hi << 16);
        }
    }
  }
  __syncthreads();  // As dead; wave regions may now be overwritten

  // unpack packed bf16 into wave-private swizzled LDS
#pragma unroll
  for (int g = 0; g < 3; ++g)
#pragma unroll
    for (int nt2 = 0; nt2 < 2; ++nt2) {
      const int d = nt2 * 16 + l15;
#pragma unroll
      for (int mi = 0; mi < 4; ++mi)
#pragma unroll
        for (int rp = 0; rp < 2; ++rp) {
          const uint w2 = pk[g][nt2 * 8 + mi * 2 + rp];
          const int tok0 = mi * 16 + quad * 4 + rp * 2;
          const ushort v0 = (ushort)(w2 & 0xffffu);
          const ushort v1 = (ushort)(w2 >> 16);
          if (g == 0) {
            Qs[qk_idx(tok0, d)] = v0;
            Qs[qk_idx(tok0 + 1, d)] = v1;
          } else if (g == 1) {
            Ks[qk_idx(tok0, d)] = v0;
            Ks[qk_idx(tok0 + 1, d)] = v1;
          } else {
            Vt[v_idx(d, tok0)] = v0;
            Vt[v_idx(d, tok0 + 1)] = v1;
          }
        }
    }

  // ---- QK^T ----
  short8 qf[4], kf[4];
#pragma unroll
  for (int i = 0; i < 4; ++i) {
    const int row = i * 16 + l15;
    qf[i] = *(const short8*)&Qs[qk_idx(row, quad * 8)];
    kf[i] = *(const short8*)&Ks[qk_idx(row, quad * 8)];
  }
  floatx4 S[4][4];
#pragma unroll
  for (int i = 0; i < 4; ++i)
#pragma unroll
    for (int j = 0; j < 4; ++j) S[i][j] = {0.f, 0.f, 0.f, 0.f};
#pragma unroll
  for (int mi = 0; mi < 4; ++mi)
#pragma unroll
    for (int nj = 0; nj < 4; ++nj)
      S[mi][nj] = __builtin_amdgcn_mfma_f32_16x16x32_bf16(
          qf[mi], kf[nj], S[mi][nj], 0, 0, 0);

  // scale + swin mask
  const int wy = (gw >> 3) & 7, wx = gw & 7;
#pragma unroll
  for (int mi = 0; mi < 4; ++mi)
#pragma unroll
    for (int nj = 0; nj < 4; ++nj)
#pragma unroll
      for (int r = 0; r < 4; ++r) S[mi][nj][r] *= SCALE;
  if (pass) {
    int ridc[4];
#pragma unroll
    for (int nj = 0; nj < 4; ++nj) ridc[nj] = region_id(wy, wx, nj * 16 + l15);
#pragma unroll
    for (int mi = 0; mi < 4; ++mi)
#pragma unroll
      for (int r = 0; r < 4; ++r) {
        const int rr = region_id(wy, wx, mi * 16 + quad * 4 + r);
#pragma unroll
        for (int nj = 0; nj < 4; ++nj)
          if (rr != ridc[nj]) S[mi][nj][r] += NEGM;
      }
  }

  // softmax per row; write P (bf16) to Ps (aliases Q|K, now dead)
#pragma unroll
  for (int mi = 0; mi < 4; ++mi) {
#pragma unroll
    for (int r = 0; r < 4; ++r) {
      float mx = fmaxf(fmaxf(S[mi][0][r], S[mi][1][r]),
                       fmaxf(S[mi][2][r], S[mi][3][r]));
#pragma unroll
      for (int o = 1; o < 16; o <<= 1) mx = fmaxf(mx, __shfl_xor(mx, o));
      float sm_ = 0.f;
#pragma unroll
      for (int nj = 0; nj < 4; ++nj) {
        float e = __expf(S[mi][nj][r] - mx);
        S[mi][nj][r] = e;
        sm_ += e;
      }
#pragma unroll
      for (int o = 1; o < 16; o <<= 1) sm_ += __shfl_xor(sm_, o);
      const float inv = 1.f / sm_;
      const int row = mi * 16 + quad * 4 + r;
#pragma unroll
      for (int nj = 0; nj < 4; ++nj)
        Ps[p_idx(row, nj * 16 + l15)] = f2b(S[mi][nj][r] * inv);
    }
  }

  // ---- PV: A = P (LDS), B = V^T (LDS) ----
  floatx4 O[4][2];
#pragma unroll
  for (int i = 0; i < 4; ++i) {
    O[i][0] = {0.f, 0.f, 0.f, 0.f};
    O[i][1] = {0.f, 0.f, 0.f, 0.f};
  }
#pragma unroll
  for (int ks = 0; ks < 2; ++ks) {
    short8 bfr[2];
#pragma unroll
    for (int n2 = 0; n2 < 2; ++n2)
      bfr[n2] = *(const short8*)&Vt[v_idx(n2 * 16 + l15, ks * 32 + quad * 8)];
#pragma unroll
    for (int mi = 0; mi < 4; ++mi) {
      short8 af2 = *(const short8*)&Ps[p_idx(mi * 16 + l15, ks * 32 + quad * 8)];
#pragma unroll
      for (int n2 = 0; n2 < 2; ++n2)
        O[mi][n2] = __builtin_amdgcn_mfma_f32_16x16x32_bf16(
            af2, bfr[n2], O[mi][n2], 0, 0, 0);
    }
  }

  // store bf16 [win][tok][256]
  ushort* ob = attn_out + (size_t)wi * 16384 + hh * 32;
#pragma unroll
  for (int mi = 0; mi < 4; ++mi)
#pragma unroll
    for (int r = 0; r < 4; ++r) {
      const int s = mi * 16 + quad * 4 + r;
      ob[s * 256 + l15]      = f2b(O[mi][0][r]);
      ob[s * 256 + 16 + l15] = f2b(O[mi][1][r]);
    }
}

// ---------------------------------------------------------------------------
// K2: out-proj GEMM (bf16 A). pass0: scatter bf16 into pass-1 window layout
// of xw (fuses window_reverse + roll + window_partition). pass1: fp32 out.
// ---------------------------------------------------------------------------
__global__ __launch_bounds__(256) void proj_mfma_kernel(
    const ushort* __restrict__ attn, const ushort* __restrict__ BT,
    const float* __restrict__ bo, float* __restrict__ out,
    ushort* __restrict__ xw, int w0, int pass) {
  __shared__ ushort As[128][72];
  __shared__ ushort Bs[128][72];
  const int t = threadIdx.x;
  const int lane = t & 63, wv = t >> 6;
  const int wm = wv >> 1, wn = wv & 1;
  const int quad = lane >> 4, l15 = lane & 15;
  const int sr = t >> 1, sh = (t & 1) * 32;
  const int bn0 = blockIdx.x * 128, row0 = blockIdx.y * 128;

  floatx4 acc[4][4];
#pragma unroll
  for (int i = 0; i < 4; ++i)
#pragma unroll
    for (int j = 0; j < 4; ++j) acc[i][j] = {0.f, 0.f, 0.f, 0.f};

  const ushort* arow = attn + (size_t)(row0 + sr) * 256 + sh;
  const ushort* brow = BT + (size_t)(bn0 + sr) * 256 + sh;

  for (int kc = 0; kc < 4; ++kc) {
    const int k0 = kc * 64;
#pragma unroll
    for (int u = 0; u < 4; ++u) {
      *(uint4*)&As[sr][sh + u * 8] = *(const uint4*)(arow + k0 + u * 8);
      *(uint4*)&Bs[sr][sh + u * 8] = *(const uint4*)(brow + k0 + u * 8);
    }
    __syncthreads();
#pragma unroll
    for (int ks = 0; ks < 2; ++ks) {
      const int ko = ks * 32 + quad * 8;
      short8 af[4], bf[4];
#pragma unroll
      for (int i = 0; i < 4; ++i) {
        af[i] = *(const short8*)&As[wm * 64 + i * 16 + l15][ko];
        bf[i] = *(const short8*)&Bs[wn * 64 + i * 16 + l15][ko];
      }
#pragma unroll
      for (int mi = 0; mi < 4; ++mi)
#pragma unroll
        for (int nj = 0; nj < 4; ++nj)
          acc[mi][nj] = __builtin_amdgcn_mfma_f32_16x16x32_bf16(
              af[mi], bf[nj], acc[mi][nj], 0, 0, 0);
    }
    __syncthreads();
  }

  float bias[4];
  int ncol[4];
#pragma unroll
  for (int nj = 0; nj < 4; ++nj) {
    ncol[nj] = bn0 + wn * 64 + nj * 16 + l15;
    bias[nj] = bo[ncol[nj]];
  }
#pragma unroll
  for (int mi = 0; mi < 4; ++mi)
#pragma unroll
    for (int r = 0; r < 4; ++r) {
      const int gr = row0 + wm * 64 + mi * 16 + quad * 4 + r;
      int m, h, w;
      win_coords(pass, w0 + (gr >> 6), gr & 63, m, h, w);
      if (pass == 0) {
        const int h2 = (h - 4) & 63, w2 = (w - 4) & 63;
        const int row2 = ((m * 64 + (h2 >> 3) * 8 + (w2 >> 3)) << 6) +
                         (h2 & 7) * 8 + (w2 & 7);
        ushort* xrow = xw + (size_t)row2 * 256;
#pragma unroll
        for (int nj = 0; nj < 4; ++nj)
          xrow[ncol[nj]] = f2b(acc[mi][nj][r] + bias[nj]);
      } else {
        float* orow = out + (size_t)((m * 64 + h) * 64 + w) * 256;
#pragma unroll
        for (int nj = 0; nj < 4; ++nj)
          orow[ncol[nj]] = acc[mi][nj][r] + bias[nj];
      }
    }
}

// ---------------------------------------------------------------------------
extern "C" void kernel_launch(void* const* d_in, const int* in_sizes, int n_in,
                              void* d_out, int out_size, void* d_ws, size_t ws_size,
                              hipStream_t stream) {
  (void)in_sizes; (void)n_in; (void)out_size;
  const float* x    = (const float*)d_in[0];
  const float* wqkv = (const float*)d_in[1];
  const float* bqkv = (const float*)d_in[2];
  const float* wo   = (const float*)d_in[3];
  const float* bo   = (const float*)d_in[4];
  float* out = (float*)d_out;

  // ws: wqkvT(384K) | woT(128K) | xw bf16 (64M, pass-1 input) | attn chunks
  ushort* wqkvT = (ushort*)d_ws;
  ushort* woT   = (ushort*)((char*)d_ws + 393216);
  ushort* xw    = (ushort*)((char*)d_ws + 524288);
  char* chunkbase = (char*)d_ws + 524288 + 67108864;
  size_t fixed = 524288 + 67108864;
  size_t rem = (ws_size > fixed) ? (ws_size - fixed) : 0;
  int S = 1;
  while (S < 1024 && (size_t)(2048 / S) * 32768 > rem) S <<= 1;
  const int CW = 2048 / S;
  ushort* attnws = (ushort*)chunkbase;  // CW*32768 B

  wtrans_kernel<<<dim3(1024), dim3(256), 0, stream>>>(wqkv, wo, wqkvT, woT);

  for (int pass = 0; pass < 2; ++pass) {
    for (int c = 0; c < S; ++c) {
      const int w0 = c * CW;
      qkvattn_kernel<<<dim3(CW * 2), dim3(256), 0, stream>>>(
          x, xw + (size_t)w0 * 16384, wqkvT, bqkv, attnws, w0, pass);
      proj_mfma_kernel<<<dim3(2, CW / 2), dim3(256), 0, stream>>>(
          attnws, woT, bo, out, xw, w0, pass);
    }
  }
}